// Round 1
// baseline (431.401 us; speedup 1.0000x reference)
//
#include <hip/hip_runtime.h>
#include <math.h>

#define EMB 256

// OUT[m][n] = sum_k X[m][k] * W[n][k] + bias[n]
// X: [M][EMB] row-major, W: [N=256][EMB] row-major (nn.Linear layout), OUT: [M][256]
// Block: 256 threads (16x16), tile BM=128 x BN=128, BK=32, 8x8 per thread.
__global__ __launch_bounds__(256, 2)
void gemm_xwT(const float* __restrict__ X, const float* __restrict__ W,
              const float* __restrict__ bias, float* __restrict__ OUT, int M)
{
    const int BM = 128, BN = 128, BK = 32;
    // transposed tiles: [k][m] so compute reads are contiguous float4s
    __shared__ float xs[32][BM + 4];   // stride 132 floats = 528B (16B aligned)
    __shared__ float wsh[32][BN + 4];

    const int tid = threadIdx.x;
    const int m0 = blockIdx.x * BM;
    const int n0 = blockIdx.y * BN;
    const int tx = tid & 15;       // n-dim
    const int ty = tid >> 4;       // m-dim

    float acc[8][8];
#pragma unroll
    for (int i = 0; i < 8; ++i)
#pragma unroll
        for (int j = 0; j < 8; ++j) acc[i][j] = 0.0f;

    const int f4   = tid & 7;      // which float4 along k (BK=32 -> 8 float4)
    const int row0 = tid >> 3;     // 0..31

    for (int k0 = 0; k0 < EMB; k0 += BK) {
        // stage X tile (BM rows x BK cols), transposed into xs[k][m]
#pragma unroll
        for (int p = 0; p < BM / 32; ++p) {
            const int row = row0 + p * 32;
            const int gm = m0 + row;
            float4 v = make_float4(0.f, 0.f, 0.f, 0.f);
            if (gm < M) v = *(const float4*)&X[(size_t)gm * EMB + k0 + f4 * 4];
            xs[f4 * 4 + 0][row] = v.x;
            xs[f4 * 4 + 1][row] = v.y;
            xs[f4 * 4 + 2][row] = v.z;
            xs[f4 * 4 + 3][row] = v.w;
        }
        // stage W tile (BN rows x BK cols), transposed into wsh[k][n]
#pragma unroll
        for (int p = 0; p < BN / 32; ++p) {
            const int row = row0 + p * 32;
            const float4 v = *(const float4*)&W[(size_t)(n0 + row) * EMB + k0 + f4 * 4];
            wsh[f4 * 4 + 0][row] = v.x;
            wsh[f4 * 4 + 1][row] = v.y;
            wsh[f4 * 4 + 2][row] = v.z;
            wsh[f4 * 4 + 3][row] = v.w;
        }
        __syncthreads();

#pragma unroll 4
        for (int kk = 0; kk < BK; ++kk) {
            const float4 a0 = *(const float4*)&xs[kk][ty * 8];
            const float4 a1 = *(const float4*)&xs[kk][ty * 8 + 4];
            const float4 b0 = *(const float4*)&wsh[kk][tx * 8];
            const float4 b1 = *(const float4*)&wsh[kk][tx * 8 + 4];
            const float a[8] = {a0.x, a0.y, a0.z, a0.w, a1.x, a1.y, a1.z, a1.w};
            const float b[8] = {b0.x, b0.y, b0.z, b0.w, b1.x, b1.y, b1.z, b1.w};
#pragma unroll
            for (int i = 0; i < 8; ++i)
#pragma unroll
                for (int j = 0; j < 8; ++j)
                    acc[i][j] += a[i] * b[j];
        }
        __syncthreads();
    }

    // epilogue: add bias, store 2 float4 per output row
    float bn[8];
#pragma unroll
    for (int j = 0; j < 8; ++j) bn[j] = bias[n0 + tx * 8 + j];

#pragma unroll
    for (int i = 0; i < 8; ++i) {
        const int gm = m0 + ty * 8 + i;
        if (gm < M) {
            float4 o0, o1;
            o0.x = acc[i][0] + bn[0]; o0.y = acc[i][1] + bn[1];
            o0.z = acc[i][2] + bn[2]; o0.w = acc[i][3] + bn[3];
            o1.x = acc[i][4] + bn[4]; o1.y = acc[i][5] + bn[5];
            o1.z = acc[i][6] + bn[6]; o1.w = acc[i][7] + bn[7];
            float* dst = &OUT[(size_t)gm * EMB + n0 + tx * 8];
            *(float4*)dst = o0;
            *(float4*)(dst + 4) = o1;
        }
    }
}

// One wave (64 lanes) per edge: gather H[src], T[dst], rel[type] rows (float4/lane),
// triple-product partial sums, wave shuffle-reduce, sigmoid.
__global__ __launch_bounds__(256)
void edge_score(const float* __restrict__ H, const float* __restrict__ T,
                const float* __restrict__ rel, const int* __restrict__ ei,
                const int* __restrict__ et, float* __restrict__ out, int E)
{
    const int lane = threadIdx.x & 63;
    const int wid = threadIdx.x >> 6;
    const int e = blockIdx.x * 4 + wid;
    if (e >= E) return;

    const int src = ei[e];
    const int dst = ei[E + e];
    const int r = et[e];

    const float4 h = *(const float4*)&H[(size_t)src * EMB + lane * 4];
    const float4 t = *(const float4*)&T[(size_t)dst * EMB + lane * 4];
    const float4 g = *(const float4*)&rel[(size_t)r * EMB + lane * 4];

    float s = h.x * g.x * t.x + h.y * g.y * t.y + h.z * g.z * t.z + h.w * g.w * t.w;
#pragma unroll
    for (int off = 32; off > 0; off >>= 1)
        s += __shfl_xor(s, off, 64);

    if (lane == 0) out[e] = 1.0f / (1.0f + expf(-s));
}

// Fallback (only if ws too small): one block per edge, compute both matvecs directly.
__global__ __launch_bounds__(256)
void edge_direct(const float* __restrict__ X, const int* __restrict__ ei,
                 const int* __restrict__ et,
                 const float* __restrict__ Wh, const float* __restrict__ bh,
                 const float* __restrict__ Wt, const float* __restrict__ bt,
                 const float* __restrict__ rel, float* __restrict__ out, int E)
{
    __shared__ float xsrc[EMB], xdst[EMB];
    __shared__ float red[256];
    const int e = blockIdx.x;
    const int tid = threadIdx.x;
    const int src = ei[e], dst = ei[E + e], r = et[e];

    xsrc[tid] = X[(size_t)src * EMB + tid];
    xdst[tid] = X[(size_t)dst * EMB + tid];
    __syncthreads();

    float ah = 0.f, at = 0.f;
    const float* wh = Wh + (size_t)tid * EMB;
    const float* wt = Wt + (size_t)tid * EMB;
#pragma unroll 8
    for (int k = 0; k < EMB; k += 4) {
        float4 w4 = *(const float4*)&wh[k];
        ah += w4.x * xsrc[k] + w4.y * xsrc[k + 1] + w4.z * xsrc[k + 2] + w4.w * xsrc[k + 3];
        float4 v4 = *(const float4*)&wt[k];
        at += v4.x * xdst[k] + v4.y * xdst[k + 1] + v4.z * xdst[k + 2] + v4.w * xdst[k + 3];
    }
    red[tid] = (ah + bh[tid]) * rel[(size_t)r * EMB + tid] * (at + bt[tid]);
    __syncthreads();
    for (int s2 = 128; s2 > 0; s2 >>= 1) {
        if (tid < s2) red[tid] += red[tid + s2];
        __syncthreads();
    }
    if (tid == 0) out[e] = 1.0f / (1.0f + expf(-red[0]));
}

extern "C" void kernel_launch(void* const* d_in, const int* in_sizes, int n_in,
                              void* d_out, int out_size, void* d_ws, size_t ws_size,
                              hipStream_t stream) {
    const float* x   = (const float*)d_in[0];
    const int*   ei  = (const int*)d_in[1];
    const int*   et  = (const int*)d_in[2];
    const float* Wh  = (const float*)d_in[3];
    const float* bh  = (const float*)d_in[4];
    const float* Wt  = (const float*)d_in[5];
    const float* bt  = (const float*)d_in[6];
    const float* rel = (const float*)d_in[7];
    float* out = (float*)d_out;

    const int M = in_sizes[0] / EMB;   // 100000 nodes
    const int E = in_sizes[2];         // 250000 edges

    const size_t need = (size_t)2 * M * EMB * sizeof(float);
    if (ws_size >= need) {
        float* H = (float*)d_ws;
        float* T = H + (size_t)M * EMB;
        dim3 grid((M + 127) / 128, EMB / 128);
        gemm_xwT<<<grid, 256, 0, stream>>>(x, Wh, bh, H, M);
        gemm_xwT<<<grid, 256, 0, stream>>>(x, Wt, bt, T, M);
        edge_score<<<(E + 3) / 4, 256, 0, stream>>>(H, T, rel, ei, et, out, E);
    } else {
        edge_direct<<<E, 256, 0, stream>>>(x, ei, et, Wh, bh, Wt, bt, rel, out, E);
    }
}